// Round 1
// baseline (1443.959 us; speedup 1.0000x reference)
//
#include <hip/hip_runtime.h>
#include <hip/hip_bf16.h>
#include <math.h>

#define NN     100000
#define NFEATD 512
#define NHIDD  256
#define NCLS   40
#define NE     1600000
#define KHOP   10

// ---------- helpers ----------
static __device__ __forceinline__ float bf2f(unsigned int u) {
  unsigned int x = u << 16;
  float f;
  __builtin_memcpy(&f, &x, 4);
  return f;
}
static __device__ __forceinline__ unsigned short f2bf(float f) {
  unsigned int x;
  __builtin_memcpy(&x, &f, 4);
  x = (x + 0x7fffu + ((x >> 16) & 1u)) >> 16;
  return (unsigned short)x;
}

// ---------- GEMM1: h1 = relu(x @ W1 + b1), bf16 out ----------
// 64x64 tile per block, 256 threads (16x16), 4x4 per thread, Kt=32.
__global__ __launch_bounds__(256) void gemm1_kernel(
    const float* __restrict__ x, const float* __restrict__ W1,
    const float* __restrict__ b1, unsigned short* __restrict__ h1) {
  __shared__ float xs[32][72];   // transposed: xs[k][row], padded
  __shared__ float wsm[32][72];  // wsm[k][col], padded
  const int tid = threadIdx.x;
  const int ty = tid >> 4, tx = tid & 15;
  const int r0 = blockIdx.x * 64;
  const int c0 = blockIdx.y * 64;

  float acc[4][4];
#pragma unroll
  for (int i = 0; i < 4; ++i)
#pragma unroll
    for (int j = 0; j < 4; ++j) acc[i][j] = 0.f;

  for (int kt = 0; kt < NFEATD; kt += 32) {
    // stage x tile (transposed into LDS)
    int l = tid;
#pragma unroll
    for (int rep = 0; rep < 2; ++rep, l += 256) {
      int lrow = l >> 3;           // 0..63
      int lk = (l & 7) << 2;       // 0..28 step 4
      int row = r0 + lrow;
      float4 v = make_float4(0.f, 0.f, 0.f, 0.f);
      if (row < NN) v = *(const float4*)(x + row * NFEATD + kt + lk);
      xs[lk + 0][lrow] = v.x;
      xs[lk + 1][lrow] = v.y;
      xs[lk + 2][lrow] = v.z;
      xs[lk + 3][lrow] = v.w;
    }
    // stage W1 tile
    l = tid;
#pragma unroll
    for (int rep = 0; rep < 2; ++rep, l += 256) {
      int wk = l >> 4;             // 0..31
      int wc = (l & 15) << 2;      // 0..60 step 4
      float4 v = *(const float4*)(W1 + (kt + wk) * NHIDD + c0 + wc);
      *(float4*)&wsm[wk][wc] = v;
    }
    __syncthreads();
#pragma unroll
    for (int k = 0; k < 32; ++k) {
      const float4 a = *(const float4*)&xs[k][ty << 2];
      const float4 b = *(const float4*)&wsm[k][tx << 2];
      float av[4] = {a.x, a.y, a.z, a.w};
      float bv[4] = {b.x, b.y, b.z, b.w};
#pragma unroll
      for (int i = 0; i < 4; ++i)
#pragma unroll
        for (int j = 0; j < 4; ++j) acc[i][j] = fmaf(av[i], bv[j], acc[i][j]);
    }
    __syncthreads();
  }

  float bias[4];
#pragma unroll
  for (int j = 0; j < 4; ++j) bias[j] = b1[c0 + (tx << 2) + j];
#pragma unroll
  for (int i = 0; i < 4; ++i) {
    int row = r0 + (ty << 2) + i;
    if (row < NN) {
      ushort4 o;
      o.x = f2bf(fmaxf(acc[i][0] + bias[0], 0.f));
      o.y = f2bf(fmaxf(acc[i][1] + bias[1], 0.f));
      o.z = f2bf(fmaxf(acc[i][2] + bias[2], 0.f));
      o.w = f2bf(fmaxf(acc[i][3] + bias[3], 0.f));
      *(ushort4*)(h1 + row * NHIDD + c0 + (tx << 2)) = o;
    }
  }
}

// ---------- GEMM2: h = h1(bf16) @ W2 + b2 ----------
__global__ __launch_bounds__(256) void gemm2_kernel(
    const unsigned short* __restrict__ h1, const float* __restrict__ W2,
    const float* __restrict__ b2, float* __restrict__ h) {
  __shared__ float w2s[NHIDD * NCLS];  // 40 KB
  __shared__ float b2s[NCLS];
  __shared__ unsigned short h1s[64 * 264];  // padded stride
  const int tid = threadIdx.x;
  const int r0 = blockIdx.x * 64;
  for (int i = tid; i < NHIDD * NCLS; i += 256) w2s[i] = W2[i];
  if (tid < NCLS) b2s[tid] = b2[tid];
#pragma unroll
  for (int q = 0; q < 8; ++q) {
    int l = tid + q * 256;     // 0..2047
    int lr = l >> 5;           // 0..63
    int lc = (l & 31) << 3;    // 0..248 step 8 (ushorts)
    int row = r0 + lr;
    uint4 v = make_uint4(0, 0, 0, 0);
    if (row < NN) v = *(const uint4*)(h1 + row * NHIDD + lc);
    *(uint4*)&h1s[lr * 264 + lc] = v;
  }
  __syncthreads();
  const int lr = tid >> 2;
  const int cq = (tid & 3) * 10;
  float acc[10];
#pragma unroll
  for (int j = 0; j < 10; ++j) acc[j] = 0.f;
#pragma unroll 4
  for (int k = 0; k < NHIDD; k += 2) {
    unsigned int hp = *(const unsigned int*)&h1s[lr * 264 + k];
    float a0 = bf2f(hp & 0xffffu);
    float a1 = bf2f(hp >> 16);
    const float* w0 = &w2s[k * NCLS + cq];
    const float* w1 = &w2s[(k + 1) * NCLS + cq];
#pragma unroll
    for (int j = 0; j < 10; ++j)
      acc[j] = fmaf(a1, w1[j], fmaf(a0, w0[j], acc[j]));
  }
  int row = r0 + lr;
  if (row < NN) {
#pragma unroll
    for (int j = 0; j < 10; ++j) h[row * NCLS + cq + j] = acc[j] + b2s[cq + j];
  }
}

// ---------- CSR build ----------
__global__ __launch_bounds__(256) void zero_kernel(int* __restrict__ p, int n) {
  int i = blockIdx.x * 256 + threadIdx.x;
  if (i < n) p[i] = 0;
}
__global__ __launch_bounds__(256) void count_kernel(const int* __restrict__ edst,
                                                    int* __restrict__ counts) {
  int e = blockIdx.x * 256 + threadIdx.x;
  if (e < NE) atomicAdd(&counts[edst[e]], 1);
}
__global__ __launch_bounds__(256) void scan_blocks_kernel(
    const int* __restrict__ counts, int* __restrict__ row_start,
    int* __restrict__ bsum) {
  __shared__ int s[256];
  int gid = blockIdx.x * 256 + threadIdx.x;
  int v = (gid < NN) ? counts[gid] : 0;
  s[threadIdx.x] = v;
  __syncthreads();
  for (int off = 1; off < 256; off <<= 1) {
    int t = (threadIdx.x >= off) ? s[threadIdx.x - off] : 0;
    __syncthreads();
    s[threadIdx.x] += t;
    __syncthreads();
  }
  if (gid < NN) row_start[gid + 1] = s[threadIdx.x];
  if (threadIdx.x == 255) bsum[blockIdx.x] = s[255];
}
#define NB 391
__global__ __launch_bounds__(512) void scan_sums_kernel(int* __restrict__ bsum) {
  __shared__ int s[512];
  int tid = threadIdx.x;
  int v = (tid < NB) ? bsum[tid] : 0;
  s[tid] = v;
  __syncthreads();
  for (int off = 1; off < 512; off <<= 1) {
    int t = (tid >= off) ? s[tid - off] : 0;
    __syncthreads();
    s[tid] += t;
    __syncthreads();
  }
  if (tid < NB) bsum[tid] = (tid == 0) ? 0 : s[tid - 1];  // exclusive
}
__global__ __launch_bounds__(256) void add_off_kernel(int* __restrict__ row_start,
                                                      const int* __restrict__ bsum) {
  int gid = blockIdx.x * 256 + threadIdx.x;
  if (gid < NN) row_start[gid + 1] += bsum[blockIdx.x];
  if (gid == 0) row_start[0] = 0;
}
__global__ __launch_bounds__(256) void scatter_kernel(
    const int* __restrict__ esrc, const int* __restrict__ edst,
    const float* __restrict__ eval, const int* __restrict__ row_start,
    int* __restrict__ cursor, int* __restrict__ csr_src,
    float* __restrict__ csr_val) {
  int e = blockIdx.x * 256 + threadIdx.x;
  if (e < NE) {
    int d = edst[e];
    int p = atomicAdd(&cursor[d], 1);
    int idx = row_start[d] + p;
    csr_src[idx] = esrc[e];
    csr_val[idx] = eval[e];
  }
}

// ---------- propagation: zo = 0.9 * (A z) + 0.1 * h ----------
__global__ __launch_bounds__(256) void prop_kernel(
    const int* __restrict__ row_start, const int* __restrict__ csr_src,
    const float* __restrict__ csr_val, const float* __restrict__ z,
    const float* __restrict__ h, float* __restrict__ zo) {
  int t = blockIdx.x * 256 + threadIdx.x;
  if (t >= NN * 10) return;
  unsigned int r = (unsigned int)t / 10u;
  int cg = t - (int)r * 10;
  int e0 = row_start[r], e1 = row_start[r + 1];
  float4 acc = make_float4(0.f, 0.f, 0.f, 0.f);
  for (int e = e0; e < e1; ++e) {
    int s = csr_src[e];
    float v = csr_val[e];
    const float4 zv = *(const float4*)(z + s * NCLS + cg * 4);
    acc.x = fmaf(v, zv.x, acc.x);
    acc.y = fmaf(v, zv.y, acc.y);
    acc.z = fmaf(v, zv.z, acc.z);
    acc.w = fmaf(v, zv.w, acc.w);
  }
  const float4 hv = *(const float4*)(h + r * NCLS + cg * 4);
  float4 o;
  o.x = 0.9f * acc.x + 0.1f * hv.x;
  o.y = 0.9f * acc.y + 0.1f * hv.y;
  o.z = 0.9f * acc.z + 0.1f * hv.z;
  o.w = 0.9f * acc.w + 0.1f * hv.w;
  *(float4*)(zo + r * NCLS + cg * 4) = o;
}

// ---------- log_softmax (in place) ----------
__global__ __launch_bounds__(256) void lsm_kernel(float* __restrict__ zio) {
  int r = blockIdx.x * 256 + threadIdx.x;
  if (r >= NN) return;
  float v[NCLS];
#pragma unroll
  for (int q = 0; q < 10; ++q) {
    float4 t = *(const float4*)(zio + r * NCLS + q * 4);
    v[q * 4 + 0] = t.x;
    v[q * 4 + 1] = t.y;
    v[q * 4 + 2] = t.z;
    v[q * 4 + 3] = t.w;
  }
  float m = v[0];
#pragma unroll
  for (int i = 1; i < NCLS; ++i) m = fmaxf(m, v[i]);
  float ssum = 0.f;
#pragma unroll
  for (int i = 0; i < NCLS; ++i) ssum += expf(v[i] - m);
  float lse = m + logf(ssum);
#pragma unroll
  for (int q = 0; q < 10; ++q) {
    float4 t;
    t.x = v[q * 4 + 0] - lse;
    t.y = v[q * 4 + 1] - lse;
    t.z = v[q * 4 + 2] - lse;
    t.w = v[q * 4 + 3] - lse;
    *(float4*)(zio + r * NCLS + q * 4) = t;
  }
}

extern "C" void kernel_launch(void* const* d_in, const int* in_sizes, int n_in,
                              void* d_out, int out_size, void* d_ws, size_t ws_size,
                              hipStream_t stream) {
  const float* x = (const float*)d_in[0];
  const int* esrc = (const int*)d_in[1];
  const int* edst = (const int*)d_in[2];
  const float* eval = (const float*)d_in[3];
  const float* W1 = (const float*)d_in[4];
  const float* b1 = (const float*)d_in[5];
  const float* W2 = (const float*)d_in[6];
  const float* b2 = (const float*)d_in[7];
  float* out = (float*)d_out;
  char* ws = (char*)d_ws;

  // workspace layout (bytes), ~97.2 MB total
  float* h = (float*)(ws + 0);                           // 16,000,000
  float* zA = (float*)(ws + 16000000);                   // 16,000,000
  unsigned short* h1 = (unsigned short*)(ws + 32000000); // 51,200,000
  int* counts = (int*)(ws + 83200000);                   // 400,000
  int* cursor = (int*)(ws + 83600000);                   // 400,000
  int* row_start = (int*)(ws + 84000000);                // 400,004 (+pad)
  int* bsum = (int*)(ws + 84400640);                     // 2,048
  int* csr_src = (int*)(ws + 84402688);                  // 6,400,000
  float* csr_val = (float*)(ws + 90802688);              // 6,400,000

  // zero counts + cursor (adjacent: 200,000 ints)
  zero_kernel<<<(2 * NN + 255) / 256, 256, 0, stream>>>(counts, 2 * NN);

  // MLP
  gemm1_kernel<<<dim3((NN + 63) / 64, NHIDD / 64), 256, 0, stream>>>(x, W1, b1, h1);
  gemm2_kernel<<<(NN + 63) / 64, 256, 0, stream>>>(h1, W2, b2, h);

  // CSR build
  count_kernel<<<(NE + 255) / 256, 256, 0, stream>>>(edst, counts);
  scan_blocks_kernel<<<NB, 256, 0, stream>>>(counts, row_start, bsum);
  scan_sums_kernel<<<1, 512, 0, stream>>>(bsum);
  add_off_kernel<<<NB, 256, 0, stream>>>(row_start, bsum);
  scatter_kernel<<<(NE + 255) / 256, 256, 0, stream>>>(esrc, edst, eval, row_start,
                                                       cursor, csr_src, csr_val);

  // propagation, ping-pong h -> zA -> out -> zA ... (K=10 ends in out)
  const float* zin = h;
  float* zout = zA;
  for (int i = 0; i < KHOP; ++i) {
    prop_kernel<<<(NN * 10 + 255) / 256, 256, 0, stream>>>(row_start, csr_src,
                                                           csr_val, zin, h, zout);
    if (i == 0) {
      zin = zA;
      zout = out;
    } else {
      float* t = (float*)zin;
      zin = zout;
      zout = t;
    }
  }

  // log_softmax in place on out
  lsm_kernel<<<(NN + 255) / 256, 256, 0, stream>>>(out);
}

// Round 2
// 1250.469 us; speedup vs baseline: 1.1547x; 1.1547x over previous
//
#include <hip/hip_runtime.h>
#include <hip/hip_bf16.h>
#include <math.h>

#define NN     100000
#define NFEATD 512
#define NHIDD  256
#define NCLS   40
#define NE     1600000
#define KHOP   10

typedef __attribute__((ext_vector_type(8))) short short8;
typedef __attribute__((ext_vector_type(4))) float floatx4;

// ---------- helpers ----------
static __device__ __forceinline__ float bf2f(unsigned int u) {
  unsigned int x = u << 16;
  float f;
  __builtin_memcpy(&f, &x, 4);
  return f;
}
static __device__ __forceinline__ unsigned short f2bf(float f) {
  unsigned int x;
  __builtin_memcpy(&x, &f, 4);
  x = (x + 0x7fffu + ((x >> 16) & 1u)) >> 16;
  return (unsigned short)x;
}

// ---------- W1 [512][256] fp32 -> Wt [256][512] bf16 ----------
__global__ __launch_bounds__(256) void wt_kernel(const float* __restrict__ W1,
                                                 unsigned short* __restrict__ Wt) {
  int i = blockIdx.x * 256 + threadIdx.x;  // over 512*256
  int k = i >> 8;
  int n = i & 255;
  Wt[n * 512 + k] = f2bf(W1[i]);
}

// ---------- GEMM1 (MFMA): h1 = relu(x @ W1 + b1), bf16 out ----------
// 128x128 tile, 256 threads = 4 waves (2x2), each wave 64x64 via 4x4 mfma 16x16x32.
__global__ __launch_bounds__(256) void gemm1_mfma_kernel(
    const float* __restrict__ x, const unsigned short* __restrict__ Wt,
    const float* __restrict__ b1, unsigned short* __restrict__ h1) {
  __shared__ unsigned short As[128 * 40];  // row stride 40 shorts (80B)
  __shared__ unsigned short Bs[128 * 40];
  const int tid = threadIdx.x;
  const int lane = tid & 63;
  const int wave = tid >> 6;
  const int wr = wave >> 1, wc = wave & 1;
  const int m = lane & 15, quad = lane >> 4;
  const int c0 = blockIdx.x * 128;  // col block (0 or 128)
  const int r0 = blockIdx.y * 128;  // row block

  // staging coords (fixed per thread)
  const int arow = tid >> 3;   // 0..31 (+rep*32)
  const int akq = tid & 7;     // float4 index within row (k = akq*4)
  const int brow = tid >> 2;   // 0..63 (+rep*64)
  const int bkq = tid & 3;     // 16B chunk within row (k = bkq*8)

  floatx4 acc[4][4];
#pragma unroll
  for (int i = 0; i < 4; ++i)
#pragma unroll
    for (int j = 0; j < 4; ++j) acc[i][j] = (floatx4){0.f, 0.f, 0.f, 0.f};

  for (int kt = 0; kt < NFEATD; kt += 32) {
    // stage A: x fp32 -> bf16, 128 rows x 32 k
#pragma unroll
    for (int rep = 0; rep < 4; ++rep) {
      int row = arow + rep * 32;
      int grow = r0 + row;
      float4 v = make_float4(0.f, 0.f, 0.f, 0.f);
      if (grow < NN) v = *(const float4*)(x + grow * NFEATD + kt + akq * 4);
      ushort4 o;
      o.x = f2bf(v.x);
      o.y = f2bf(v.y);
      o.z = f2bf(v.z);
      o.w = f2bf(v.w);
      *(ushort4*)&As[row * 40 + akq * 4] = o;
    }
    // stage B: Wt bf16, 128 n-rows x 32 k
#pragma unroll
    for (int rep = 0; rep < 2; ++rep) {
      int row = brow + rep * 64;
      uint4 v = *(const uint4*)(Wt + (c0 + row) * NFEATD + kt + bkq * 8);
      *(uint4*)&Bs[row * 40 + bkq * 8] = v;
    }
    __syncthreads();

    short8 af[4], bfr[4];
#pragma unroll
    for (int i = 0; i < 4; ++i)
      af[i] = *(const short8*)&As[(wr * 64 + i * 16 + m) * 40 + quad * 8];
#pragma unroll
    for (int j = 0; j < 4; ++j)
      bfr[j] = *(const short8*)&Bs[(wc * 64 + j * 16 + m) * 40 + quad * 8];
#pragma unroll
    for (int i = 0; i < 4; ++i)
#pragma unroll
      for (int j = 0; j < 4; ++j)
        acc[i][j] = __builtin_amdgcn_mfma_f32_16x16x32_bf16(af[i], bfr[j], acc[i][j], 0, 0, 0);
    __syncthreads();
  }

  // epilogue: C/D layout col=lane&15, row=quad*4+reg
  float bias[4];
#pragma unroll
  for (int j = 0; j < 4; ++j) bias[j] = b1[c0 + wc * 64 + j * 16 + m];
#pragma unroll
  for (int i = 0; i < 4; ++i) {
#pragma unroll
    for (int r = 0; r < 4; ++r) {
      int row = r0 + wr * 64 + i * 16 + quad * 4 + r;
      if (row < NN) {
#pragma unroll
        for (int j = 0; j < 4; ++j) {
          float v = acc[i][j][r] + bias[j];
          h1[row * NHIDD + c0 + wc * 64 + j * 16 + m] = f2bf(fmaxf(v, 0.f));
        }
      }
    }
  }
}

// ---------- GEMM2: h = h1(bf16) @ W2 + b2 ----------
__global__ __launch_bounds__(256) void gemm2_kernel(
    const unsigned short* __restrict__ h1, const float* __restrict__ W2,
    const float* __restrict__ b2, float* __restrict__ h) {
  __shared__ float w2s[NHIDD * NCLS];  // 40 KB
  __shared__ float b2s[NCLS];
  __shared__ unsigned short h1s[64 * 264];  // padded stride
  const int tid = threadIdx.x;
  const int r0 = blockIdx.x * 64;
  for (int i = tid; i < NHIDD * NCLS; i += 256) w2s[i] = W2[i];
  if (tid < NCLS) b2s[tid] = b2[tid];
#pragma unroll
  for (int q = 0; q < 8; ++q) {
    int l = tid + q * 256;     // 0..2047
    int lr = l >> 5;           // 0..63
    int lc = (l & 31) << 3;    // 0..248 step 8 (ushorts)
    int row = r0 + lr;
    uint4 v = make_uint4(0, 0, 0, 0);
    if (row < NN) v = *(const uint4*)(h1 + row * NHIDD + lc);
    *(uint4*)&h1s[lr * 264 + lc] = v;
  }
  __syncthreads();
  const int lr = tid >> 2;
  const int cq = (tid & 3) * 10;
  float acc[10];
#pragma unroll
  for (int j = 0; j < 10; ++j) acc[j] = 0.f;
#pragma unroll 4
  for (int k = 0; k < NHIDD; k += 2) {
    unsigned int hp = *(const unsigned int*)&h1s[lr * 264 + k];
    float a0 = bf2f(hp & 0xffffu);
    float a1 = bf2f(hp >> 16);
    const float* w0 = &w2s[k * NCLS + cq];
    const float* w1 = &w2s[(k + 1) * NCLS + cq];
#pragma unroll
    for (int j = 0; j < 10; ++j)
      acc[j] = fmaf(a1, w1[j], fmaf(a0, w0[j], acc[j]));
  }
  int row = r0 + lr;
  if (row < NN) {
#pragma unroll
    for (int j = 0; j < 10; ++j) h[row * NCLS + cq + j] = acc[j] + b2s[cq + j];
  }
}

// ---------- CSR build ----------
__global__ __launch_bounds__(256) void zero_kernel(int* __restrict__ p, int n) {
  int i = blockIdx.x * 256 + threadIdx.x;
  if (i < n) p[i] = 0;
}
__global__ __launch_bounds__(256) void count_kernel(const int* __restrict__ edst,
                                                    int* __restrict__ counts) {
  int e = blockIdx.x * 256 + threadIdx.x;
  if (e < NE) atomicAdd(&counts[edst[e]], 1);
}
__global__ __launch_bounds__(256) void scan_blocks_kernel(
    const int* __restrict__ counts, int* __restrict__ row_start,
    int* __restrict__ bsum) {
  __shared__ int s[256];
  int gid = blockIdx.x * 256 + threadIdx.x;
  int v = (gid < NN) ? counts[gid] : 0;
  s[threadIdx.x] = v;
  __syncthreads();
  for (int off = 1; off < 256; off <<= 1) {
    int t = (threadIdx.x >= off) ? s[threadIdx.x - off] : 0;
    __syncthreads();
    s[threadIdx.x] += t;
    __syncthreads();
  }
  if (gid < NN) row_start[gid + 1] = s[threadIdx.x];
  if (threadIdx.x == 255) bsum[blockIdx.x] = s[255];
}
#define NB 391
__global__ __launch_bounds__(512) void scan_sums_kernel(int* __restrict__ bsum) {
  __shared__ int s[512];
  int tid = threadIdx.x;
  int v = (tid < NB) ? bsum[tid] : 0;
  s[tid] = v;
  __syncthreads();
  for (int off = 1; off < 512; off <<= 1) {
    int t = (tid >= off) ? s[tid - off] : 0;
    __syncthreads();
    s[tid] += t;
    __syncthreads();
  }
  if (tid < NB) bsum[tid] = (tid == 0) ? 0 : s[tid - 1];  // exclusive
}
__global__ __launch_bounds__(256) void add_off_kernel(int* __restrict__ row_start,
                                                      const int* __restrict__ bsum) {
  int gid = blockIdx.x * 256 + threadIdx.x;
  if (gid < NN) row_start[gid + 1] += bsum[blockIdx.x];
  if (gid == 0) row_start[0] = 0;
}
__global__ __launch_bounds__(256) void scatter_kernel(
    const int* __restrict__ esrc, const int* __restrict__ edst,
    const float* __restrict__ eval, const int* __restrict__ row_start,
    int* __restrict__ cursor, int* __restrict__ csr_src,
    float* __restrict__ csr_val) {
  int e = blockIdx.x * 256 + threadIdx.x;
  if (e < NE) {
    int d = edst[e];
    int p = atomicAdd(&cursor[d], 1);
    int idx = row_start[d] + p;
    csr_src[idx] = esrc[e];
    csr_val[idx] = eval[e];
  }
}

// ---------- propagation: zo = 0.9 * (A z) + 0.1 * h ----------
__global__ __launch_bounds__(256) void prop_kernel(
    const int* __restrict__ row_start, const int* __restrict__ csr_src,
    const float* __restrict__ csr_val, const float* __restrict__ z,
    const float* __restrict__ h, float* __restrict__ zo) {
  int t = blockIdx.x * 256 + threadIdx.x;
  if (t >= NN * 10) return;
  unsigned int r = (unsigned int)t / 10u;
  int cg = t - (int)r * 10;
  int e0 = row_start[r], e1 = row_start[r + 1];
  float4 acc = make_float4(0.f, 0.f, 0.f, 0.f);
  for (int e = e0; e < e1; ++e) {
    int s = csr_src[e];
    float v = csr_val[e];
    const float4 zv = *(const float4*)(z + s * NCLS + cg * 4);
    acc.x = fmaf(v, zv.x, acc.x);
    acc.y = fmaf(v, zv.y, acc.y);
    acc.z = fmaf(v, zv.z, acc.z);
    acc.w = fmaf(v, zv.w, acc.w);
  }
  const float4 hv = *(const float4*)(h + r * NCLS + cg * 4);
  float4 o;
  o.x = 0.9f * acc.x + 0.1f * hv.x;
  o.y = 0.9f * acc.y + 0.1f * hv.y;
  o.z = 0.9f * acc.z + 0.1f * hv.z;
  o.w = 0.9f * acc.w + 0.1f * hv.w;
  *(float4*)(zo + r * NCLS + cg * 4) = o;
}

// ---------- log_softmax (in place) ----------
__global__ __launch_bounds__(256) void lsm_kernel(float* __restrict__ zio) {
  int r = blockIdx.x * 256 + threadIdx.x;
  if (r >= NN) return;
  float v[NCLS];
#pragma unroll
  for (int q = 0; q < 10; ++q) {
    float4 t = *(const float4*)(zio + r * NCLS + q * 4);
    v[q * 4 + 0] = t.x;
    v[q * 4 + 1] = t.y;
    v[q * 4 + 2] = t.z;
    v[q * 4 + 3] = t.w;
  }
  float m = v[0];
#pragma unroll
  for (int i = 1; i < NCLS; ++i) m = fmaxf(m, v[i]);
  float ssum = 0.f;
#pragma unroll
  for (int i = 0; i < NCLS; ++i) ssum += expf(v[i] - m);
  float lse = m + logf(ssum);
#pragma unroll
  for (int q = 0; q < 10; ++q) {
    float4 t;
    t.x = v[q * 4 + 0] - lse;
    t.y = v[q * 4 + 1] - lse;
    t.z = v[q * 4 + 2] - lse;
    t.w = v[q * 4 + 3] - lse;
    *(float4*)(zio + r * NCLS + q * 4) = t;
  }
}

extern "C" void kernel_launch(void* const* d_in, const int* in_sizes, int n_in,
                              void* d_out, int out_size, void* d_ws, size_t ws_size,
                              hipStream_t stream) {
  const float* x = (const float*)d_in[0];
  const int* esrc = (const int*)d_in[1];
  const int* edst = (const int*)d_in[2];
  const float* eval = (const float*)d_in[3];
  const float* W1 = (const float*)d_in[4];
  const float* b1 = (const float*)d_in[5];
  const float* W2 = (const float*)d_in[6];
  const float* b2 = (const float*)d_in[7];
  float* out = (float*)d_out;
  char* ws = (char*)d_ws;

  // workspace layout (bytes), ~97.2 MB total
  float* h = (float*)(ws + 0);                           // 16,000,000
  float* zA = (float*)(ws + 16000000);                   // 16,000,000 (doubles as Wt before prop)
  unsigned short* Wt = (unsigned short*)(ws + 16000000); // 262,144 (dead once prop starts)
  unsigned short* h1 = (unsigned short*)(ws + 32000000); // 51,200,000
  int* counts = (int*)(ws + 83200000);                   // 400,000
  int* cursor = (int*)(ws + 83600000);                   // 400,000
  int* row_start = (int*)(ws + 84000000);                // 400,004 (+pad)
  int* bsum = (int*)(ws + 84400640);                     // 2,048
  int* csr_src = (int*)(ws + 84402688);                  // 6,400,000
  float* csr_val = (float*)(ws + 90802688);              // 6,400,000

  // zero counts + cursor (adjacent: 200,000 ints)
  zero_kernel<<<(2 * NN + 255) / 256, 256, 0, stream>>>(counts, 2 * NN);

  // MLP
  wt_kernel<<<(NFEATD * NHIDD) / 256, 256, 0, stream>>>(W1, Wt);
  gemm1_mfma_kernel<<<dim3(2, (NN + 127) / 128), 256, 0, stream>>>(x, Wt, b1, h1);
  gemm2_kernel<<<(NN + 63) / 64, 256, 0, stream>>>(h1, W2, b2, h);

  // CSR build
  count_kernel<<<(NE + 255) / 256, 256, 0, stream>>>(edst, counts);
  scan_blocks_kernel<<<NB, 256, 0, stream>>>(counts, row_start, bsum);
  scan_sums_kernel<<<1, 512, 0, stream>>>(bsum);
  add_off_kernel<<<NB, 256, 0, stream>>>(row_start, bsum);
  scatter_kernel<<<(NE + 255) / 256, 256, 0, stream>>>(esrc, edst, eval, row_start,
                                                       cursor, csr_src, csr_val);

  // propagation, ping-pong h -> zA -> out -> zA ... (K=10 ends in out)
  const float* zin = h;
  float* zout = zA;
  for (int i = 0; i < KHOP; ++i) {
    prop_kernel<<<(NN * 10 + 255) / 256, 256, 0, stream>>>(row_start, csr_src,
                                                           csr_val, zin, h, zout);
    if (i == 0) {
      zin = zA;
      zout = out;
    } else {
      float* t = (float*)zin;
      zin = zout;
      zout = t;
    }
  }

  // log_softmax in place on out
  lsm_kernel<<<(NN + 255) / 256, 256, 0, stream>>>(out);
}

// Round 3
// 1157.933 us; speedup vs baseline: 1.2470x; 1.0799x over previous
//
#include <hip/hip_runtime.h>
#include <hip/hip_bf16.h>
#include <math.h>

#define NN     100000
#define NFEATD 512
#define NHIDD  256
#define NCLS   40
#define NE     1600000
#define KHOP   10

typedef __attribute__((ext_vector_type(8))) short short8;
typedef __attribute__((ext_vector_type(4))) float floatx4;

// ---------- helpers ----------
static __device__ __forceinline__ float bf2f(unsigned int u) {
  unsigned int x = u << 16;
  float f;
  __builtin_memcpy(&f, &x, 4);
  return f;
}
static __device__ __forceinline__ unsigned short f2bf(float f) {
  unsigned int x;
  __builtin_memcpy(&x, &x, 0);  // no-op to keep compiler happy on some builds
  __builtin_memcpy(&x, &f, 4);
  x = (x + 0x7fffu + ((x >> 16) & 1u)) >> 16;
  return (unsigned short)x;
}

// ---------- W1 [512][256] fp32 -> Wt [256][512] bf16 ----------
__global__ __launch_bounds__(256) void wt_kernel(const float* __restrict__ W1,
                                                 unsigned short* __restrict__ Wt) {
  int i = blockIdx.x * 256 + threadIdx.x;  // over 512*256
  int k = i >> 8;
  int n = i & 255;
  Wt[n * 512 + k] = f2bf(W1[i]);
}

// ---------- GEMM1 (MFMA, software-pipelined): h1 = relu(x @ W1 + b1) ----------
// 128x128 tile, 256 threads = 4 waves (2x2), each wave 64x64 via 4x4 mfma 16x16x32.
__global__ __launch_bounds__(256) void gemm1_mfma_kernel(
    const float* __restrict__ x, const unsigned short* __restrict__ Wt,
    const float* __restrict__ b1, unsigned short* __restrict__ h1) {
  __shared__ unsigned short As[128 * 40];  // row stride 40 shorts (80B)
  __shared__ unsigned short Bs[128 * 40];
  const int tid = threadIdx.x;
  const int lane = tid & 63;
  const int wave = tid >> 6;
  const int wr = wave >> 1, wc = wave & 1;
  const int m = lane & 15, quad = lane >> 4;
  const int c0 = blockIdx.x * 128;  // col block (0 or 128)
  const int r0 = blockIdx.y * 128;  // row block

  // staging coords (fixed per thread)
  const int arow = tid >> 3;   // 0..31 (+rep*32)
  const int akq = tid & 7;     // float4 index within row (k = akq*4)
  const int brow = tid >> 2;   // 0..63 (+rep*64)
  const int bkq = tid & 3;     // 16B chunk within row (k = bkq*8)

  floatx4 acc[4][4];
#pragma unroll
  for (int i = 0; i < 4; ++i)
#pragma unroll
    for (int j = 0; j < 4; ++j) acc[i][j] = (floatx4){0.f, 0.f, 0.f, 0.f};

  float4 aR[4];
  uint4 bR[2];
  // prologue: load tile kt=0 into regs
#pragma unroll
  for (int rep = 0; rep < 4; ++rep) {
    int grow = r0 + arow + rep * 32;
    aR[rep] = make_float4(0.f, 0.f, 0.f, 0.f);
    if (grow < NN) aR[rep] = *(const float4*)(x + grow * NFEATD + akq * 4);
  }
#pragma unroll
  for (int rep = 0; rep < 2; ++rep)
    bR[rep] = *(const uint4*)(Wt + (c0 + brow + rep * 64) * NFEATD + bkq * 8);

  for (int kt = 0; kt < NFEATD; kt += 32) {
    // stage regs -> LDS (fused fp32->bf16 for A)
#pragma unroll
    for (int rep = 0; rep < 4; ++rep) {
      ushort4 o;
      o.x = f2bf(aR[rep].x);
      o.y = f2bf(aR[rep].y);
      o.z = f2bf(aR[rep].z);
      o.w = f2bf(aR[rep].w);
      *(ushort4*)&As[(arow + rep * 32) * 40 + akq * 4] = o;
    }
#pragma unroll
    for (int rep = 0; rep < 2; ++rep)
      *(uint4*)&Bs[(brow + rep * 64) * 40 + bkq * 8] = bR[rep];
    __syncthreads();

    // issue NEXT tile's global loads (regs are free now); waitcnt lands next iter
    int ktn = kt + 32;
    if (ktn < NFEATD) {
#pragma unroll
      for (int rep = 0; rep < 4; ++rep) {
        int grow = r0 + arow + rep * 32;
        float4 v = make_float4(0.f, 0.f, 0.f, 0.f);
        if (grow < NN) v = *(const float4*)(x + grow * NFEATD + ktn + akq * 4);
        aR[rep] = v;
      }
#pragma unroll
      for (int rep = 0; rep < 2; ++rep)
        bR[rep] = *(const uint4*)(Wt + (c0 + brow + rep * 64) * NFEATD + ktn + bkq * 8);
    }

    // fragments + MFMA on current tile
    short8 af[4], bfr[4];
#pragma unroll
    for (int i = 0; i < 4; ++i)
      af[i] = *(const short8*)&As[(wr * 64 + i * 16 + m) * 40 + quad * 8];
#pragma unroll
    for (int j = 0; j < 4; ++j)
      bfr[j] = *(const short8*)&Bs[(wc * 64 + j * 16 + m) * 40 + quad * 8];
#pragma unroll
    for (int i = 0; i < 4; ++i)
#pragma unroll
      for (int j = 0; j < 4; ++j)
        acc[i][j] = __builtin_amdgcn_mfma_f32_16x16x32_bf16(af[i], bfr[j], acc[i][j], 0, 0, 0);
    __syncthreads();
  }

  // epilogue: C/D layout col=lane&15, row=quad*4+reg
  float bias[4];
#pragma unroll
  for (int j = 0; j < 4; ++j) bias[j] = b1[c0 + wc * 64 + j * 16 + m];
#pragma unroll
  for (int i = 0; i < 4; ++i) {
#pragma unroll
    for (int r = 0; r < 4; ++r) {
      int row = r0 + wr * 64 + i * 16 + quad * 4 + r;
      if (row < NN) {
#pragma unroll
        for (int j = 0; j < 4; ++j) {
          float v = acc[i][j][r] + bias[j];
          h1[row * NHIDD + c0 + wc * 64 + j * 16 + m] = f2bf(fmaxf(v, 0.f));
        }
      }
    }
  }
}

// ---------- GEMM2: h = h1(bf16) @ W2 + b2 ----------
__global__ __launch_bounds__(256) void gemm2_kernel(
    const unsigned short* __restrict__ h1, const float* __restrict__ W2,
    const float* __restrict__ b2, float* __restrict__ h) {
  __shared__ float w2s[NHIDD * NCLS];  // 40 KB
  __shared__ float b2s[NCLS];
  __shared__ unsigned short h1s[64 * 264];  // padded stride
  const int tid = threadIdx.x;
  const int r0 = blockIdx.x * 64;
  for (int i = tid; i < NHIDD * NCLS; i += 256) w2s[i] = W2[i];
  if (tid < NCLS) b2s[tid] = b2[tid];
#pragma unroll
  for (int q = 0; q < 8; ++q) {
    int l = tid + q * 256;     // 0..2047
    int lr = l >> 5;           // 0..63
    int lc = (l & 31) << 3;    // 0..248 step 8 (ushorts)
    int row = r0 + lr;
    uint4 v = make_uint4(0, 0, 0, 0);
    if (row < NN) v = *(const uint4*)(h1 + row * NHIDD + lc);
    *(uint4*)&h1s[lr * 264 + lc] = v;
  }
  __syncthreads();
  const int lr = tid >> 2;
  const int cq = (tid & 3) * 10;
  float acc[10];
#pragma unroll
  for (int j = 0; j < 10; ++j) acc[j] = 0.f;
#pragma unroll 4
  for (int k = 0; k < NHIDD; k += 2) {
    unsigned int hp = *(const unsigned int*)&h1s[lr * 264 + k];
    float a0 = bf2f(hp & 0xffffu);
    float a1 = bf2f(hp >> 16);
    const float* w0 = &w2s[k * NCLS + cq];
    const float* w1 = &w2s[(k + 1) * NCLS + cq];
#pragma unroll
    for (int j = 0; j < 10; ++j)
      acc[j] = fmaf(a1, w1[j], fmaf(a0, w0[j], acc[j]));
  }
  int row = r0 + lr;
  if (row < NN) {
#pragma unroll
    for (int j = 0; j < 10; ++j) h[row * NCLS + cq + j] = acc[j] + b2s[cq + j];
  }
}

// ---------- CSR build ----------
__global__ __launch_bounds__(256) void zero_kernel(int* __restrict__ p, int n) {
  int i = blockIdx.x * 256 + threadIdx.x;
  if (i < n) p[i] = 0;
}
__global__ __launch_bounds__(256) void count_kernel(const int* __restrict__ edst,
                                                    int* __restrict__ counts) {
  int e = blockIdx.x * 256 + threadIdx.x;
  if (e < NE) atomicAdd(&counts[edst[e]], 1);
}
__global__ __launch_bounds__(256) void scan_blocks_kernel(
    const int* __restrict__ counts, int* __restrict__ row_start,
    int* __restrict__ bsum) {
  __shared__ int s[256];
  int gid = blockIdx.x * 256 + threadIdx.x;
  int v = (gid < NN) ? counts[gid] : 0;
  s[threadIdx.x] = v;
  __syncthreads();
  for (int off = 1; off < 256; off <<= 1) {
    int t = (threadIdx.x >= off) ? s[threadIdx.x - off] : 0;
    __syncthreads();
    s[threadIdx.x] += t;
    __syncthreads();
  }
  if (gid < NN) row_start[gid + 1] = s[threadIdx.x];
  if (threadIdx.x == 255) bsum[blockIdx.x] = s[255];
}
#define NB 391
__global__ __launch_bounds__(512) void scan_sums_kernel(int* __restrict__ bsum) {
  __shared__ int s[512];
  int tid = threadIdx.x;
  int v = (tid < NB) ? bsum[tid] : 0;
  s[tid] = v;
  __syncthreads();
  for (int off = 1; off < 512; off <<= 1) {
    int t = (tid >= off) ? s[tid - off] : 0;
    __syncthreads();
    s[tid] += t;
    __syncthreads();
  }
  if (tid < NB) bsum[tid] = (tid == 0) ? 0 : s[tid - 1];  // exclusive
}
__global__ __launch_bounds__(256) void add_off_kernel(int* __restrict__ row_start,
                                                      const int* __restrict__ bsum) {
  int gid = blockIdx.x * 256 + threadIdx.x;
  if (gid < NN) row_start[gid + 1] += bsum[blockIdx.x];
  if (gid == 0) row_start[0] = 0;
}
__global__ __launch_bounds__(256) void scatter_kernel(
    const int* __restrict__ esrc, const int* __restrict__ edst,
    const float* __restrict__ eval, const int* __restrict__ row_start,
    int* __restrict__ cursor, int2* __restrict__ csr_pair) {
  int e = blockIdx.x * 256 + threadIdx.x;
  if (e < NE) {
    int d = edst[e];
    int p = atomicAdd(&cursor[d], 1);
    int idx = row_start[d] + p;
    csr_pair[idx] = make_int2(esrc[e], __float_as_int(eval[e]));
  }
}

// ---------- propagation: zo = 0.9 * (A z) + 0.1 * h ----------
__global__ __launch_bounds__(256) void prop_kernel(
    const int* __restrict__ row_start, const int2* __restrict__ csr_pair,
    const float* __restrict__ z, const float* __restrict__ h,
    float* __restrict__ zo) {
  int t = blockIdx.x * 256 + threadIdx.x;
  if (t >= NN * 10) return;
  unsigned int r = (unsigned int)t / 10u;
  int cg = t - (int)r * 10;
  const float* zc = z + cg * 4;
  int e0 = row_start[r], e1 = row_start[r + 1];
  float4 acc = make_float4(0.f, 0.f, 0.f, 0.f);
  int e = e0;
  // unroll by 4: batch independent pair-loads, then independent gathers
  for (; e + 4 <= e1; e += 4) {
    int2 p0 = csr_pair[e + 0];
    int2 p1 = csr_pair[e + 1];
    int2 p2 = csr_pair[e + 2];
    int2 p3 = csr_pair[e + 3];
    const float4 z0 = *(const float4*)(zc + p0.x * 40);
    const float4 z1 = *(const float4*)(zc + p1.x * 40);
    const float4 z2 = *(const float4*)(zc + p2.x * 40);
    const float4 z3 = *(const float4*)(zc + p3.x * 40);
    float v0 = __int_as_float(p0.y), v1 = __int_as_float(p1.y);
    float v2 = __int_as_float(p2.y), v3 = __int_as_float(p3.y);
    acc.x = fmaf(v0, z0.x, acc.x);
    acc.y = fmaf(v0, z0.y, acc.y);
    acc.z = fmaf(v0, z0.z, acc.z);
    acc.w = fmaf(v0, z0.w, acc.w);
    acc.x = fmaf(v1, z1.x, acc.x);
    acc.y = fmaf(v1, z1.y, acc.y);
    acc.z = fmaf(v1, z1.z, acc.z);
    acc.w = fmaf(v1, z1.w, acc.w);
    acc.x = fmaf(v2, z2.x, acc.x);
    acc.y = fmaf(v2, z2.y, acc.y);
    acc.z = fmaf(v2, z2.z, acc.z);
    acc.w = fmaf(v2, z2.w, acc.w);
    acc.x = fmaf(v3, z3.x, acc.x);
    acc.y = fmaf(v3, z3.y, acc.y);
    acc.z = fmaf(v3, z3.z, acc.z);
    acc.w = fmaf(v3, z3.w, acc.w);
  }
  for (; e < e1; ++e) {
    int2 p = csr_pair[e];
    float v = __int_as_float(p.y);
    const float4 zv = *(const float4*)(zc + p.x * 40);
    acc.x = fmaf(v, zv.x, acc.x);
    acc.y = fmaf(v, zv.y, acc.y);
    acc.z = fmaf(v, zv.z, acc.z);
    acc.w = fmaf(v, zv.w, acc.w);
  }
  const float4 hv = *(const float4*)(h + r * NCLS + cg * 4);
  float4 o;
  o.x = 0.9f * acc.x + 0.1f * hv.x;
  o.y = 0.9f * acc.y + 0.1f * hv.y;
  o.z = 0.9f * acc.z + 0.1f * hv.z;
  o.w = 0.9f * acc.w + 0.1f * hv.w;
  *(float4*)(zo + r * NCLS + cg * 4) = o;
}

// ---------- log_softmax (in place) ----------
__global__ __launch_bounds__(256) void lsm_kernel(float* __restrict__ zio) {
  int r = blockIdx.x * 256 + threadIdx.x;
  if (r >= NN) return;
  float v[NCLS];
#pragma unroll
  for (int q = 0; q < 10; ++q) {
    float4 t = *(const float4*)(zio + r * NCLS + q * 4);
    v[q * 4 + 0] = t.x;
    v[q * 4 + 1] = t.y;
    v[q * 4 + 2] = t.z;
    v[q * 4 + 3] = t.w;
  }
  float m = v[0];
#pragma unroll
  for (int i = 1; i < NCLS; ++i) m = fmaxf(m, v[i]);
  float ssum = 0.f;
#pragma unroll
  for (int i = 0; i < NCLS; ++i) ssum += expf(v[i] - m);
  float lse = m + logf(ssum);
#pragma unroll
  for (int q = 0; q < 10; ++q) {
    float4 t;
    t.x = v[q * 4 + 0] - lse;
    t.y = v[q * 4 + 1] - lse;
    t.z = v[q * 4 + 2] - lse;
    t.w = v[q * 4 + 3] - lse;
    *(float4*)(zio + r * NCLS + q * 4) = t;
  }
}

extern "C" void kernel_launch(void* const* d_in, const int* in_sizes, int n_in,
                              void* d_out, int out_size, void* d_ws, size_t ws_size,
                              hipStream_t stream) {
  const float* x = (const float*)d_in[0];
  const int* esrc = (const int*)d_in[1];
  const int* edst = (const int*)d_in[2];
  const float* eval = (const float*)d_in[3];
  const float* W1 = (const float*)d_in[4];
  const float* b1 = (const float*)d_in[5];
  const float* W2 = (const float*)d_in[6];
  const float* b2 = (const float*)d_in[7];
  float* out = (float*)d_out;
  char* ws = (char*)d_ws;

  // workspace layout (bytes), ~97.2 MB total
  float* h = (float*)(ws + 0);                           // 16,000,000
  float* zA = (float*)(ws + 16000000);                   // 16,000,000 (doubles as Wt before prop)
  unsigned short* Wt = (unsigned short*)(ws + 16000000); // 262,144 (dead once prop starts)
  unsigned short* h1 = (unsigned short*)(ws + 32000000); // 51,200,000
  int* counts = (int*)(ws + 83200000);                   // 400,000
  int* cursor = (int*)(ws + 83600000);                   // 400,000
  int* row_start = (int*)(ws + 84000000);                // 400,004 (+pad)
  int* bsum = (int*)(ws + 84400640);                     // 2,048
  int2* csr_pair = (int2*)(ws + 84402688);               // 12,800,000

  // zero counts + cursor (adjacent: 200,000 ints)
  zero_kernel<<<(2 * NN + 255) / 256, 256, 0, stream>>>(counts, 2 * NN);

  // MLP
  wt_kernel<<<(NFEATD * NHIDD) / 256, 256, 0, stream>>>(W1, Wt);
  gemm1_mfma_kernel<<<dim3(2, (NN + 127) / 128), 256, 0, stream>>>(x, Wt, b1, h1);
  gemm2_kernel<<<(NN + 63) / 64, 256, 0, stream>>>(h1, W2, b2, h);

  // CSR build
  count_kernel<<<(NE + 255) / 256, 256, 0, stream>>>(edst, counts);
  scan_blocks_kernel<<<NB, 256, 0, stream>>>(counts, row_start, bsum);
  scan_sums_kernel<<<1, 512, 0, stream>>>(bsum);
  add_off_kernel<<<NB, 256, 0, stream>>>(row_start, bsum);
  scatter_kernel<<<(NE + 255) / 256, 256, 0, stream>>>(esrc, edst, eval, row_start,
                                                       cursor, csr_pair);

  // propagation, ping-pong h -> zA -> out -> zA ... (K=10 ends in out)
  const float* zin = h;
  float* zout = zA;
  for (int i = 0; i < KHOP; ++i) {
    prop_kernel<<<(NN * 10 + 255) / 256, 256, 0, stream>>>(row_start, csr_pair,
                                                           zin, h, zout);
    if (i == 0) {
      zin = zA;
      zout = out;
    } else {
      float* t = (float*)zin;
      zin = zout;
      zout = t;
    }
  }

  // log_softmax in place on out
  lsm_kernel<<<(NN + 255) / 256, 256, 0, stream>>>(out);
}